// Round 17
// baseline (460.466 us; speedup 1.0000x reference)
//
#include <hip/hip_runtime.h>
#include <hip/hip_bf16.h>
#include <cstdint>

typedef short short8 __attribute__((ext_vector_type(8)));
typedef float floatx4 __attribute__((ext_vector_type(4)));
typedef float floatx16 __attribute__((ext_vector_type(16)));
typedef float f32x4 __attribute__((ext_vector_type(4)));
typedef unsigned short u16;
typedef unsigned short u16x4 __attribute__((ext_vector_type(4)));

#define BB 8192
#define DD 2048
#define HH 4096

static __device__ __forceinline__ u16 f2bf(float x) {
  __hip_bfloat16 h = __float2bfloat16(x);
  return __builtin_bit_cast(u16, h);
}

static __device__ __forceinline__ float bf2f(u16 x) {
  unsigned int u = ((unsigned int)x) << 16;
  return __builtin_bit_cast(float, u);
}

static __device__ __forceinline__ void glds16(const u16* g, u16* l) {
  __builtin_amdgcn_global_load_lds(
      (const __attribute__((address_space(1))) void*)g,
      (__attribute__((address_space(3))) void*)l, 16, 0, 0);
}

// richer row swizzle: distinct bank-quads for rows 8/16/24 apart (32-row
// frag spans of the 32x32 MFMA read pattern)
#define SWZ(row_) (((row_) ^ ((row_) >> 3)) & 7)

// ---------------- elementwise: value fp32 -> bf16 ----------------
__global__ void cvt_value_kernel(const float* __restrict__ in, u16* __restrict__ out, int n4) {
  int idx = blockIdx.x * blockDim.x + threadIdx.x;
  int stride = gridDim.x * blockDim.x;
  for (int i = idx; i < n4; i += stride) {
    f32x4 v = reinterpret_cast<const f32x4*>(in)[i];
    u16x4 o = { f2bf(v[0]), f2bf(v[1]), f2bf(v[2]), f2bf(v[3]) };
    reinterpret_cast<u16x4*>(out)[i] = o;
  }
}

// ---------------- tiled mask + cast weights (64x64 tiles) ----------------
template<int MODE>
__global__ __launch_bounds__(256) void mask_cvt_tile(const float* __restrict__ in,
                                                     u16* __restrict__ out, int W) {
  const int r0 = blockIdx.y * 64;
  const int c0 = blockIdx.x * 64;
  const int re = r0 + 63, ce = c0 + 63;

  bool zero;
  if (MODE == 0) {
    int rmaxd = (r0 >= 2047) ? ((re <= 4093) ? (re - 2047) : 2046)
                             : ((re <= 2046) ? re : 2046);
    zero = (c0 > rmaxd);
  } else if (MODE == 1) {
    int rmaxd = (r0 >= 2047) ? ((re <= 4093) ? (re - 2047) : 2046)
                             : ((re <= 2046) ? re : 2046);
    int cmind = (c0 >= 2047) ? ((ce >= 4094) ? 0 : (c0 - 2047))
                             : ((ce >= 2047) ? 0 : c0);
    zero = (cmind > rmaxd);
  } else {
    int cmind = (c0 >= 2047) ? ((ce >= 4094) ? 0 : (c0 - 2047))
                             : ((ce >= 2047) ? 0 : c0);
    zero = (re <= cmind);
  }

  const int tr = threadIdx.x >> 4;
  const int tc = (threadIdx.x & 15) * 4;

  if (zero) {
    u16x4 z = {0, 0, 0, 0};
#pragma unroll
    for (int rr = 0; rr < 64; rr += 16)
      *(u16x4*)&out[(size_t)(r0 + tr + rr) * W + c0 + tc] = z;
    return;
  }

#pragma unroll
  for (int rr = 0; rr < 64; rr += 16) {
    int r = r0 + tr + rr;
    int rdeg = r % 2047;
    f32x4 v = *(const f32x4*)&in[(size_t)r * W + c0 + tc];
    u16x4 o;
#pragma unroll
    for (int e = 0; e < 4; ++e) {
      int c = c0 + tc + e;
      bool keep;
      if (MODE == 0)      keep = (c <= rdeg);
      else if (MODE == 1) keep = ((c % 2047) <= rdeg);
      else                keep = (r > (c % 2047));
      o[e] = keep ? f2bf(v[e]) : (u16)0;
    }
    *(u16x4*)&out[(size_t)r * W + c0 + tc] = o;
  }
}

// ============ 256x256 GEMM with 32x32x16 MFMA (G1/G2), SWZ-fixed ========
// r16 structure with the richer swizzle SWZ(row) = (row^(row>>3))&7 applied
// both-sides (staging source + read addr). Every stage unit's row-base is a
// multiple of 64 -> (base>>3)&7 = 0, so the staging swizzle reduces to the
// arow_ expression. 32-row frag spans now hit distinct bank quads for rows
// 8/16/24 apart. C/D map: col=lane&31, row=(r&3)+8*(r>>2)+4*(lane>>5).
template<int MASKM>
__global__ __launch_bounds__(512, 2) void gemm256_kernel(
    const u16* __restrict__ A, const u16* __restrict__ Bw,
    const float* __restrict__ bias, u16* __restrict__ C,
    int M, int N, int K)
{
  __shared__ u16 ls[2][32768];   // per slot: A chunks [0,2048), B chunks [2048,4096)

  const int tid  = threadIdx.x;
  const int wid  = tid >> 6;
  const int lane = tid & 63;
  const int wm = wid >> 2, wn = wid & 3;
  const int l31 = lane & 31, hi2 = lane >> 5;

  // XCD=y-group swizzle: c = XCD, j = slot; y = 4c + (j&3), x = j>>2
  const int wg = blockIdx.x;
  const int xcd = wg & 7, j = wg >> 3;
  const int yb = (xcd << 2) | (j & 3);
  const int p  = j >> 2;
  const int brow = yb * 256;
  int cols[2];
  cols[0] = (p < 4) ? p : p + 4;
  cols[1] = (p < 4) ? 7 - p : 19 - p;

  const int arow_ = tid >> 3;                             // 0..63
  const int agsub = (tid & 7) ^ SWZ(arow_);               // pre-swizzled source sub-chunk
  size_t aB[4];
  aB[0] = (size_t)(brow +   0 + arow_) * K + agsub * 8;
  aB[1] = (size_t)(brow + 128 + arow_) * K + agsub * 8;
  aB[2] = (size_t)(brow +  64 + arow_) * K + agsub * 8;
  aB[3] = (size_t)(brow + 192 + arow_) * K + agsub * 8;
  const int aCh[4] = {0, 1024, 512, 1536};                // LDS chunk bases

#pragma unroll 1
  for (int t = 0; t < 2; ++t) {
    const int bcol = cols[t] * 256;

    int rmax;
    {
      int sC = bcol, e = bcol + 255;
      if (e <= 2046)       rmax = e;
      else if (sC <= 2046) rmax = 2046;
      else { int em = e - 2047; rmax = (em <= 2046) ? em : 2046; }
    }
    int r1end = ((rmax >> 6) + 1) << 6; if (r1end > K) r1end = K;
    int run2start, r2end;
    if (MASKM == 1) { run2start = r1end; r2end = r1end; }
    else {
      run2start = (1984 > r1end) ? 1984 : r1end;
      r2end = (((2047 + rmax) >> 6) + 1) << 6; if (r2end > K) r2end = K;
      if (r2end < run2start) r2end = run2start;
    }
    const int n1 = r1end >> 6;
    const int nt = n1 + ((r2end - run2start) >> 6);
    const int roff = run2start - r1end;
    const int nte = nt + ((MASKM != 1 && r2end < K) ? 1 : 0);

    size_t bB[2][2];
#pragma unroll
    for (int u = 0; u < 2; ++u)
#pragma unroll
      for (int c = 0; c < 2; ++c)
        bB[u][c] = (size_t)(bcol + u * 128 + arow_ + 64 * c) * K + agsub * 8;

    floatx16 acc[4][2];
#pragma unroll
    for (int i = 0; i < 4; ++i)
#pragma unroll
      for (int jj = 0; jj < 2; ++jj)
        acc[i][jj] = (floatx16)(0.0f);

#define K0F(jx) (((jx) >= nt) ? (K - 64) : (((jx) << 6) + (((jx) >= n1) ? roff : 0)))
#define ST_TILE(slot_, k0v) do { \
    glds16(A + aB[0] + (k0v), (u16*)&ls[slot_][(aCh[0] + tid) * 8]); \
    glds16(A + aB[1] + (k0v), (u16*)&ls[slot_][(aCh[1] + tid) * 8]); \
    glds16(A + aB[2] + (k0v), (u16*)&ls[slot_][(aCh[2] + tid) * 8]); \
    glds16(A + aB[3] + (k0v), (u16*)&ls[slot_][(aCh[3] + tid) * 8]); \
    glds16(Bw + bB[0][0] + (k0v), (u16*)&ls[slot_][(2048 + tid) * 8]); \
    glds16(Bw + bB[0][1] + (k0v), (u16*)&ls[slot_][(2048 + tid + 512) * 8]); \
    glds16(Bw + bB[1][0] + (k0v), (u16*)&ls[slot_][(3072 + tid) * 8]); \
    glds16(Bw + bB[1][1] + (k0v), (u16*)&ls[slot_][(3072 + tid + 512) * 8]); \
  } while (0)

    // prologue: stage tile 0 -> slot 0
    ST_TILE(0, K0F(0));
    asm volatile("s_waitcnt vmcnt(0)" ::: "memory");
    __builtin_amdgcn_sched_barrier(0);
    __builtin_amdgcn_s_barrier();
    __builtin_amdgcn_sched_barrier(0);

#pragma unroll 1
    for (int i = 0; i < nte; ++i) {
      const int s = i & 1, o = s ^ 1;
      const u16* sA = &ls[s][0];
      const u16* sB = &ls[s][16384];
      const bool g1 = (i + 1 < nte);
      short8 af[4], bfv[2];

      if (g1) ST_TILE(o, K0F(i + 1));

      // per phase ks: global k-sub-chunk g = ks*2 + hi2 (16B = 8 bf16)
#define PHASE32(ks_) do { \
      _Pragma("unroll") \
      for (int mi = 0; mi < 4; ++mi) { \
        int row = wm * 128 + mi * 32 + l31; \
        int ch = row * 8 + (((ks_) * 2 + hi2) ^ SWZ(row)); \
        af[mi] = *(const short8*)&sA[ch * 8]; \
      } \
      _Pragma("unroll") \
      for (int ni = 0; ni < 2; ++ni) { \
        int row = wn * 64 + ni * 32 + l31; \
        int ch = row * 8 + (((ks_) * 2 + hi2) ^ SWZ(row)); \
        bfv[ni] = *(const short8*)&sB[ch * 8]; \
      } \
      asm volatile("s_waitcnt lgkmcnt(0)" ::: "memory"); \
      __builtin_amdgcn_sched_barrier(0); \
      __builtin_amdgcn_s_setprio(1); \
      _Pragma("unroll") \
      for (int mi = 0; mi < 4; ++mi) \
        _Pragma("unroll") \
        for (int ni = 0; ni < 2; ++ni) \
          acc[mi][ni] = __builtin_amdgcn_mfma_f32_32x32x16_bf16( \
              af[mi], bfv[ni], acc[mi][ni], 0, 0, 0); \
      __builtin_amdgcn_s_setprio(0); \
    } while (0)

      PHASE32(0);
      PHASE32(1);
      PHASE32(2);
      PHASE32(3);
#undef PHASE32

      // tile boundary: stages for i+1 issued a full tile ago
      asm volatile("s_waitcnt vmcnt(0)" ::: "memory");
      __builtin_amdgcn_sched_barrier(0);
      __builtin_amdgcn_s_barrier();
      __builtin_amdgcn_sched_barrier(0);
    }

    // ---------- epilogue: C = relu(acc + bias) ----------
    // C/D map: col = lane&31, row = (r&3) + 8*(r>>2) + 4*hi2
#pragma unroll
    for (int mi = 0; mi < 4; ++mi) {
#pragma unroll
      for (int ni = 0; ni < 2; ++ni) {
        int col = bcol + wn * 64 + ni * 32 + l31;
        float bv = bias[col];
#pragma unroll
        for (int r = 0; r < 16; ++r) {
          int row = brow + wm * 128 + mi * 32 + (r & 3) + 8 * (r >> 2) + 4 * hi2;
          float v = acc[mi][ni][r] + bv;
          v = fmaxf(v, 0.0f);
          C[(size_t)row * N + col] = f2bf(v);
        }
      }
    }
    __syncthreads();
#undef K0F
#undef ST_TILE
  }
}

// ============ G3: 128x256 dbuf GEMM (32x32x16, SWZ) + logprob epilogue =====
__global__ __launch_bounds__(512, 2) void gemm3p_kernel(
    const u16* __restrict__ A,      // h2: BB x HH
    const u16* __restrict__ Bw,     // w3m: DD x HH
    const float* __restrict__ bias, // b3
    const u16* __restrict__ vbf,    // value bf16: BB x DD
    float* __restrict__ outp,       // BB
    int M, int N, int K)
{
  __shared__ u16 ls[2][24576];      // per slot: A elems [0,8192), B [8192,24576)

  const int tid  = threadIdx.x;
  const int wid  = tid >> 6;
  const int lane = tid & 63;
  const int wm = wid >> 2, wn = wid & 3;
  const int l31 = lane & 31, hi2 = lane >> 5;

  // XCD=y-group swizzle; heavy-first: sg = 7 - (j>>3)
  const int wg = blockIdx.x;
  const int xcd = wg & 7, j = wg >> 3;
  const int yb = (xcd << 3) | (j & 7);
  const int sg = 7 - (j >> 3);
  const int brow = yb * 128;
  const int bcol = sg * 256;

  size_t aOff[2];
#pragma unroll
  for (int u = 0; u < 2; ++u) {
    int ch = tid + 512 * u;
    int row = ch >> 3, sub = ch & 7;
    aOff[u] = (size_t)(brow + row) * K + (sub ^ SWZ(row)) * 8;
  }
  int bRow[4], bSsub[4];
#pragma unroll
  for (int u = 0; u < 4; ++u) {
    int ch = tid + 512 * u;
    bRow[u] = ch >> 3;
    bSsub[u] = (ch & 7) ^ SWZ(bRow[u]);
  }

  const int rmax = bcol + 254;

  int r1end = ((rmax >> 6) + 1) << 6; if (r1end > K) r1end = K;
  int run2start = (1984 > r1end) ? 1984 : r1end;
  int r2end = (((2047 + rmax) >> 6) + 1) << 6; if (r2end > K) r2end = K;
  if (r2end < run2start) r2end = run2start;
  const int n1 = r1end >> 6;
  const int nt = n1 + ((r2end - run2start) >> 6);
  const int roff = run2start - r1end;
  const int nte = nt + ((r2end < K) ? 1 : 0);

  size_t bOff[4];
#pragma unroll
  for (int u = 0; u < 4; ++u)
    bOff[u] = (size_t)(bcol + bRow[u]) * K + bSsub[u] * 8;

  floatx16 acc[2][2];
#pragma unroll
  for (int i = 0; i < 2; ++i)
#pragma unroll
    for (int jj = 0; jj < 2; ++jj)
      acc[i][jj] = (floatx16)(0.0f);

#define K0G(jx) (((jx) >= nt) ? (K - 64) : (((jx) << 6) + (((jx) >= n1) ? roff : 0)))
#define ST3(slot_, k0v) do { \
    glds16(A  + aOff[0] + (k0v), (u16*)&ls[slot_][tid * 8]); \
    glds16(A  + aOff[1] + (k0v), (u16*)&ls[slot_][(512 + tid) * 8]); \
    glds16(Bw + bOff[0] + (k0v), (u16*)&ls[slot_][(1024 + tid) * 8]); \
    glds16(Bw + bOff[1] + (k0v), (u16*)&ls[slot_][(1536 + tid) * 8]); \
    glds16(Bw + bOff[2] + (k0v), (u16*)&ls[slot_][(2048 + tid) * 8]); \
    glds16(Bw + bOff[3] + (k0v), (u16*)&ls[slot_][(2560 + tid) * 8]); \
  } while (0)

  ST3(0, K0G(0));
  asm volatile("s_waitcnt vmcnt(0)" ::: "memory");
  __builtin_amdgcn_sched_barrier(0);
  __builtin_amdgcn_s_barrier();
  __builtin_amdgcn_sched_barrier(0);

#pragma unroll 1
  for (int i = 0; i < nte; ++i) {
    const int s = i & 1, o = s ^ 1;
    const u16* sA = &ls[s][0];
    const u16* sB = &ls[s][8192];
    const bool g1 = (i + 1 < nte);
    short8 af[2], bfv[2];

    if (g1) ST3(o, K0G(i + 1));

#define PHASE32G3(ks_) do { \
    _Pragma("unroll") \
    for (int mi = 0; mi < 2; ++mi) { \
      int row = wm * 64 + mi * 32 + l31; \
      int ch = row * 8 + (((ks_) * 2 + hi2) ^ SWZ(row)); \
      af[mi] = *(const short8*)&sA[ch * 8]; \
    } \
    _Pragma("unroll") \
    for (int ni = 0; ni < 2; ++ni) { \
      int row = wn * 64 + ni * 32 + l31; \
      int ch = row * 8 + (((ks_) * 2 + hi2) ^ SWZ(row)); \
      bfv[ni] = *(const short8*)&sB[ch * 8]; \
    } \
    asm volatile("s_waitcnt lgkmcnt(0)" ::: "memory"); \
    __builtin_amdgcn_sched_barrier(0); \
    __builtin_amdgcn_s_setprio(1); \
    _Pragma("unroll") \
    for (int mi = 0; mi < 2; ++mi) \
      _Pragma("unroll") \
      for (int ni = 0; ni < 2; ++ni) \
        acc[mi][ni] = __builtin_amdgcn_mfma_f32_32x32x16_bf16( \
            af[mi], bfv[ni], acc[mi][ni], 0, 0, 0); \
    __builtin_amdgcn_s_setprio(0); \
  } while (0)

    PHASE32G3(0);
    PHASE32G3(1);
    PHASE32G3(2);
    PHASE32G3(3);
#undef PHASE32G3

    asm volatile("s_waitcnt vmcnt(0)" ::: "memory");
    __builtin_amdgcn_sched_barrier(0);
    __builtin_amdgcn_s_barrier();
    __builtin_amdgcn_sched_barrier(0);
  }
#undef K0G
#undef ST3

  // ---------- logprob epilogue ----------
  // C/D: col = bcol + wn*64 + ni*32 + l31;
  // row = brow + wm*64 + mi*32 + (r&3)+8*(r>>2)+4*hi2.
#pragma unroll
  for (int mi = 0; mi < 2; ++mi) {
#pragma unroll
    for (int r = 0; r < 16; ++r) {
      int row = brow + wm * 64 + mi * 32 + (r & 3) + 8 * (r >> 2) + 4 * hi2;
      float partial = 0.0f;
#pragma unroll
      for (int ni = 0; ni < 2; ++ni) {
        int col = bcol + wn * 64 + ni * 32 + l31;
        float l = acc[mi][ni][r] + bias[col];
        float v = bf2f(vbf[(size_t)row * N + col]);
        float sp = fmaxf(l, 0.0f) + __logf(1.0f + __expf(-fabsf(l)));
        partial += v * l - sp;
      }
#pragma unroll
      for (int off = 1; off < 32; off <<= 1)
        partial += __shfl_xor(partial, off, 64);
      if (l31 == 0) atomicAdd(&outp[row], partial);
    }
  }
}

// ---------------- launcher ----------------
extern "C" void kernel_launch(void* const* d_in, const int* in_sizes, int n_in,
                              void* d_out, int out_size, void* d_ws, size_t ws_size,
                              hipStream_t stream) {
  const float* value = (const float*)d_in[0];
  const float* W1 = (const float*)d_in[1];
  const float* b1 = (const float*)d_in[2];
  const float* W2 = (const float*)d_in[3];
  const float* b2 = (const float*)d_in[4];
  const float* W3 = (const float*)d_in[5];
  const float* b3 = (const float*)d_in[6];
  float* out = (float*)d_out;

  char* ws = (char*)d_ws;
  u16* vbf = (u16*)(ws);                        // B*D bf16
  u16* w1m = (u16*)(ws + 33554432ULL);          // H*D bf16
  u16* w2m = (u16*)(ws + 50331648ULL);          // H*H bf16
  u16* w3m = (u16*)(ws + 83886080ULL);          // D*H bf16
  u16* h1  = (u16*)(ws + 100663296ULL);         // B*H bf16
  u16* h2  = (u16*)(ws + 167772160ULL);         // B*H bf16

  hipMemsetAsync(d_out, 0, (size_t)out_size * sizeof(float), stream);

  cvt_value_kernel<<<2048, 256, 0, stream>>>(value, vbf, (BB * DD) / 4);
  mask_cvt_tile<0><<<dim3(DD / 64, HH / 64), 256, 0, stream>>>(W1, w1m, DD);
  mask_cvt_tile<1><<<dim3(HH / 64, HH / 64), 256, 0, stream>>>(W2, w2m, HH);
  mask_cvt_tile<2><<<dim3(HH / 64, DD / 64), 256, 0, stream>>>(W3, w3m, HH);

  gemm256_kernel<1><<<256, 512, 0, stream>>>(vbf, w1m, b1, h1, BB, HH, DD);
  gemm256_kernel<2><<<256, 512, 0, stream>>>(h1, w2m, b2, h2, BB, HH, HH);
  gemm3p_kernel<<<512, 512, 0, stream>>>(h2, w3m, b3, vbf, out, BB, DD, HH);
}

// Round 18
// 350.437 us; speedup vs baseline: 1.3140x; 1.3140x over previous
//
#include <hip/hip_runtime.h>
#include <hip/hip_bf16.h>
#include <cstdint>

typedef short short8 __attribute__((ext_vector_type(8)));
typedef float floatx4 __attribute__((ext_vector_type(4)));
typedef float f32x4 __attribute__((ext_vector_type(4)));
typedef unsigned short u16;
typedef unsigned short u16x4 __attribute__((ext_vector_type(4)));

#define BB 8192
#define DD 2048
#define HH 4096

static __device__ __forceinline__ u16 f2bf(float x) {
  __hip_bfloat16 h = __float2bfloat16(x);
  return __builtin_bit_cast(u16, h);
}

static __device__ __forceinline__ float bf2f(u16 x) {
  unsigned int u = ((unsigned int)x) << 16;
  return __builtin_bit_cast(float, u);
}

static __device__ __forceinline__ void glds16(const u16* g, u16* l) {
  __builtin_amdgcn_global_load_lds(
      (const __attribute__((address_space(1))) void*)g,
      (__attribute__((address_space(3))) void*)l, 16, 0, 0);
}

// ---------------- elementwise: value fp32 -> bf16 ----------------
__global__ void cvt_value_kernel(const float* __restrict__ in, u16* __restrict__ out, int n4) {
  int idx = blockIdx.x * blockDim.x + threadIdx.x;
  int stride = gridDim.x * blockDim.x;
  for (int i = idx; i < n4; i += stride) {
    f32x4 v = reinterpret_cast<const f32x4*>(in)[i];
    u16x4 o = { f2bf(v[0]), f2bf(v[1]), f2bf(v[2]), f2bf(v[3]) };
    reinterpret_cast<u16x4*>(out)[i] = o;
  }
}

// ---------------- tiled mask + cast weights (64x64 tiles) ----------------
template<int MODE>
__global__ __launch_bounds__(256) void mask_cvt_tile(const float* __restrict__ in,
                                                     u16* __restrict__ out, int W) {
  const int r0 = blockIdx.y * 64;
  const int c0 = blockIdx.x * 64;
  const int re = r0 + 63, ce = c0 + 63;

  bool zero;
  if (MODE == 0) {
    int rmaxd = (r0 >= 2047) ? ((re <= 4093) ? (re - 2047) : 2046)
                             : ((re <= 2046) ? re : 2046);
    zero = (c0 > rmaxd);
  } else if (MODE == 1) {
    int rmaxd = (r0 >= 2047) ? ((re <= 4093) ? (re - 2047) : 2046)
                             : ((re <= 2046) ? re : 2046);
    int cmind = (c0 >= 2047) ? ((ce >= 4094) ? 0 : (c0 - 2047))
                             : ((ce >= 2047) ? 0 : c0);
    zero = (cmind > rmaxd);
  } else {
    int cmind = (c0 >= 2047) ? ((ce >= 4094) ? 0 : (c0 - 2047))
                             : ((ce >= 2047) ? 0 : c0);
    zero = (re <= cmind);
  }

  const int tr = threadIdx.x >> 4;
  const int tc = (threadIdx.x & 15) * 4;

  if (zero) {
    u16x4 z = {0, 0, 0, 0};
#pragma unroll
    for (int rr = 0; rr < 64; rr += 16)
      *(u16x4*)&out[(size_t)(r0 + tr + rr) * W + c0 + tc] = z;
    return;
  }

#pragma unroll
  for (int rr = 0; rr < 64; rr += 16) {
    int r = r0 + tr + rr;
    int rdeg = r % 2047;
    f32x4 v = *(const f32x4*)&in[(size_t)r * W + c0 + tc];
    u16x4 o;
#pragma unroll
    for (int e = 0; e < 4; ++e) {
      int c = c0 + tc + e;
      bool keep;
      if (MODE == 0)      keep = (c <= rdeg);
      else if (MODE == 1) keep = ((c % 2047) <= rdeg);
      else                keep = (r > (c % 2047));
      o[e] = keep ? f2bf(v[e]) : (u16)0;
    }
    *(u16x4*)&out[(size_t)r * W + c0 + tc] = o;
  }
}

// ============ 256x256 de-fenced pipelined GEMM (G1/G2) ========
// r15 structure (16x16x32 MFMA, dbuf 128KB, stage i+1 at tile start, one
// vmcnt(0)+barrier per tile, XCD=y swizzle, exact two-run skip + double-wrap
// tile) with the K-loop body DE-FENCED: no manual lgkmcnt drains, no
// sched_barrier pins, no setprio. The compiler emits fine-grained counted
// lgkmcnt (m97) and interleaves ds_reads under MFMAs within the wave --
// the manual lgkmcnt(0)+sched_barrier(0) per quadrant was forcing a full
// LDS-latency stall 4x/tile (m141 failure mode).
template<int MASKM>
__global__ __launch_bounds__(512, 2) void gemm256_kernel(
    const u16* __restrict__ A, const u16* __restrict__ Bw,
    const float* __restrict__ bias, u16* __restrict__ C,
    int M, int N, int K)
{
  __shared__ u16 ls[2][32768];   // per slot: A chunks [0,2048), B chunks [2048,4096)

  const int tid  = threadIdx.x;
  const int wid  = tid >> 6;
  const int lane = tid & 63;
  const int wm = wid >> 2, wn = wid & 3;
  const int l15 = lane & 15, lhi = lane >> 4;

  // XCD=y-group swizzle: c = XCD, j = slot; y = 4c + (j&3), x = j>>2
  const int wg = blockIdx.x;
  const int xcd = wg & 7, j = wg >> 3;
  const int yb = (xcd << 2) | (j & 3);
  const int p  = j >> 2;
  const int brow = yb * 256;
  int cols[2];
  cols[0] = (p < 4) ? p : p + 4;
  cols[1] = (p < 4) ? 7 - p : 19 - p;

  const int arow_ = tid >> 3;                 // 0..63
  const int agsub = (tid & 7) ^ (arow_ & 7);  // pre-swizzled source sub-chunk
  size_t aB[4];
  aB[0] = (size_t)(brow +   0 + arow_) * K + agsub * 8;
  aB[1] = (size_t)(brow + 128 + arow_) * K + agsub * 8;
  aB[2] = (size_t)(brow +  64 + arow_) * K + agsub * 8;
  aB[3] = (size_t)(brow + 192 + arow_) * K + agsub * 8;
  const int aCh[4] = {0, 1024, 512, 1536};    // LDS chunk bases

#pragma unroll 1
  for (int t = 0; t < 2; ++t) {
    const int bcol = cols[t] * 256;

    int rmax;
    {
      int sC = bcol, e = bcol + 255;
      if (e <= 2046)       rmax = e;
      else if (sC <= 2046) rmax = 2046;
      else { int em = e - 2047; rmax = (em <= 2046) ? em : 2046; }
    }
    int r1end = ((rmax >> 6) + 1) << 6; if (r1end > K) r1end = K;
    int run2start, r2end;
    if (MASKM == 1) { run2start = r1end; r2end = r1end; }
    else {
      run2start = (1984 > r1end) ? 1984 : r1end;
      r2end = (((2047 + rmax) >> 6) + 1) << 6; if (r2end > K) r2end = K;
      if (r2end < run2start) r2end = run2start;
    }
    const int n1 = r1end >> 6;
    const int nt = n1 + ((r2end - run2start) >> 6);
    const int roff = run2start - r1end;
    const int nte = nt + ((MASKM != 1 && r2end < K) ? 1 : 0);

    size_t bB[2][2];
#pragma unroll
    for (int u = 0; u < 2; ++u)
#pragma unroll
      for (int c = 0; c < 2; ++c)
        bB[u][c] = (size_t)(bcol + u * 128 + arow_ + 64 * c) * K + agsub * 8;

    floatx4 acc[8][4];
#pragma unroll
    for (int i = 0; i < 8; ++i)
#pragma unroll
      for (int jj = 0; jj < 4; ++jj)
        acc[i][jj] = (floatx4){0.f, 0.f, 0.f, 0.f};

#define K0F(jx) (((jx) >= nt) ? (K - 64) : (((jx) << 6) + (((jx) >= n1) ? roff : 0)))
#define ST_TILE(slot_, k0v) do { \
    glds16(A + aB[0] + (k0v), (u16*)&ls[slot_][(aCh[0] + tid) * 8]); \
    glds16(A + aB[1] + (k0v), (u16*)&ls[slot_][(aCh[1] + tid) * 8]); \
    glds16(A + aB[2] + (k0v), (u16*)&ls[slot_][(aCh[2] + tid) * 8]); \
    glds16(A + aB[3] + (k0v), (u16*)&ls[slot_][(aCh[3] + tid) * 8]); \
    glds16(Bw + bB[0][0] + (k0v), (u16*)&ls[slot_][(2048 + tid) * 8]); \
    glds16(Bw + bB[0][1] + (k0v), (u16*)&ls[slot_][(2048 + tid + 512) * 8]); \
    glds16(Bw + bB[1][0] + (k0v), (u16*)&ls[slot_][(3072 + tid) * 8]); \
    glds16(Bw + bB[1][1] + (k0v), (u16*)&ls[slot_][(3072 + tid + 512) * 8]); \
  } while (0)

    // prologue: stage tile 0 -> slot 0
    ST_TILE(0, K0F(0));
    asm volatile("s_waitcnt vmcnt(0)" ::: "memory");
    __builtin_amdgcn_s_barrier();

#pragma unroll 1
    for (int i = 0; i < nte; ++i) {
      const int s = i & 1, o = s ^ 1;
      const u16* sA = &ls[s][0];
      const u16* sB = &ls[s][16384];
      const bool g1 = (i + 1 < nte);

      if (g1) ST_TILE(o, K0F(i + 1));

#define RD_A_TO(dst_, q_, ks_) do { \
      _Pragma("unroll") \
      for (int mi = 0; mi < 4; ++mi) { \
        int row = wm * 128 + (q_) * 64 + mi * 16 + l15; \
        int ch = row * 8 + (((ks_) * 4 + lhi) ^ (row & 7)); \
        dst_[mi] = *(const short8*)&sA[ch * 8]; \
      } } while (0)
#define RD_B_TO(dst_, ks_) do { \
      _Pragma("unroll") \
      for (int ni = 0; ni < 4; ++ni) { \
        int row = wn * 64 + ni * 16 + l15; \
        int ch = row * 8 + (((ks_) * 4 + lhi) ^ (row & 7)); \
        dst_[ni] = *(const short8*)&sB[ch * 8]; \
      } } while (0)
#define MFMA16(q_, afv_, bfv_) do { \
      _Pragma("unroll") \
      for (int mi = 0; mi < 4; ++mi) \
        _Pragma("unroll") \
        for (int ni = 0; ni < 4; ++ni) \
          acc[(q_) * 4 + mi][ni] = __builtin_amdgcn_mfma_f32_16x16x32_bf16( \
              afv_[mi], bfv_[ni], acc[(q_) * 4 + mi][ni], 0, 0, 0); \
      } while (0)

      // de-fenced tile body: compiler schedules reads under MFMAs with its
      // own counted lgkmcnt
      {
        short8 af0[4], af1[4], af2[4], af3[4], bf0[4], bf1[4];
        RD_A_TO(af0, 0, 0); RD_B_TO(bf0, 0);
        MFMA16(0, af0, bf0);
        RD_A_TO(af1, 0, 1); RD_B_TO(bf1, 1);
        MFMA16(0, af1, bf1);
        RD_A_TO(af2, 1, 0);
        MFMA16(1, af2, bf0);
        RD_A_TO(af3, 1, 1);
        MFMA16(1, af3, bf1);
      }

      // tile boundary: stages for i+1 issued a full tile ago
      asm volatile("s_waitcnt vmcnt(0)" ::: "memory");
      __builtin_amdgcn_s_barrier();
#undef RD_A_TO
#undef RD_B_TO
#undef MFMA16
    }

    // ---------- epilogue: C = relu(acc + bias) ----------
#pragma unroll
    for (int mi = 0; mi < 8; ++mi) {
      int row = brow + wm * 128 + (mi >> 2) * 64 + (mi & 3) * 16 + lhi * 4;
#pragma unroll
      for (int ni = 0; ni < 4; ++ni) {
        int col = bcol + wn * 64 + ni * 16 + l15;
        float bv = bias[col];
#pragma unroll
        for (int e = 0; e < 4; ++e) {
          float v = acc[mi][ni][e] + bv;
          v = fmaxf(v, 0.0f);
          C[(size_t)(row + e) * N + col] = f2bf(v);
        }
      }
    }
    __syncthreads();
#undef K0F
#undef ST_TILE
  }
}

// ============ G3: 128x256 de-fenced dbuf GEMM + logprob epilogue ===========
__global__ __launch_bounds__(512, 2) void gemm3p_kernel(
    const u16* __restrict__ A,      // h2: BB x HH
    const u16* __restrict__ Bw,     // w3m: DD x HH
    const float* __restrict__ bias, // b3
    const u16* __restrict__ vbf,    // value bf16: BB x DD
    float* __restrict__ outp,       // BB
    int M, int N, int K)
{
  __shared__ u16 ls[2][24576];      // per slot: A elems [0,8192), B [8192,24576)

  const int tid  = threadIdx.x;
  const int wid  = tid >> 6;
  const int lane = tid & 63;
  const int wm = wid >> 2, wn = wid & 3;
  const int l15 = lane & 15, lhi = lane >> 4;

  // XCD=y-group swizzle; heavy-first: sg = 7 - (j>>3)
  const int wg = blockIdx.x;
  const int xcd = wg & 7, j = wg >> 3;
  const int yb = (xcd << 3) | (j & 7);
  const int sg = 7 - (j >> 3);
  const int brow = yb * 128;
  const int bcol = sg * 256;

  size_t aOff[2];
#pragma unroll
  for (int u = 0; u < 2; ++u) {
    int ch = tid + 512 * u;
    int row = ch >> 3, sub = ch & 7;
    aOff[u] = (size_t)(brow + row) * K + (sub ^ (row & 7)) * 8;
  }
  int bRow[4], bSsub[4];
#pragma unroll
  for (int u = 0; u < 4; ++u) {
    int ch = tid + 512 * u;
    bRow[u] = ch >> 3;
    bSsub[u] = (ch & 7) ^ (bRow[u] & 7);
  }

  const int rmax = bcol + 254;

  int r1end = ((rmax >> 6) + 1) << 6; if (r1end > K) r1end = K;
  int run2start = (1984 > r1end) ? 1984 : r1end;
  int r2end = (((2047 + rmax) >> 6) + 1) << 6; if (r2end > K) r2end = K;
  if (r2end < run2start) r2end = run2start;
  const int n1 = r1end >> 6;
  const int nt = n1 + ((r2end - run2start) >> 6);
  const int roff = run2start - r1end;
  const int nte = nt + ((r2end < K) ? 1 : 0);

  size_t bOff[4];
#pragma unroll
  for (int u = 0; u < 4; ++u)
    bOff[u] = (size_t)(bcol + bRow[u]) * K + bSsub[u] * 8;

  floatx4 acc[4][4];
#pragma unroll
  for (int i = 0; i < 4; ++i)
#pragma unroll
    for (int jj = 0; jj < 4; ++jj)
      acc[i][jj] = (floatx4){0.f, 0.f, 0.f, 0.f};

#define K0G(jx) (((jx) >= nt) ? (K - 64) : (((jx) << 6) + (((jx) >= n1) ? roff : 0)))
#define ST3(slot_, k0v) do { \
    glds16(A  + aOff[0] + (k0v), (u16*)&ls[slot_][tid * 8]); \
    glds16(A  + aOff[1] + (k0v), (u16*)&ls[slot_][(512 + tid) * 8]); \
    glds16(Bw + bOff[0] + (k0v), (u16*)&ls[slot_][(1024 + tid) * 8]); \
    glds16(Bw + bOff[1] + (k0v), (u16*)&ls[slot_][(1536 + tid) * 8]); \
    glds16(Bw + bOff[2] + (k0v), (u16*)&ls[slot_][(2048 + tid) * 8]); \
    glds16(Bw + bOff[3] + (k0v), (u16*)&ls[slot_][(2560 + tid) * 8]); \
  } while (0)

  ST3(0, K0G(0));
  asm volatile("s_waitcnt vmcnt(0)" ::: "memory");
  __builtin_amdgcn_s_barrier();

#pragma unroll 1
  for (int i = 0; i < nte; ++i) {
    const int s = i & 1, o = s ^ 1;
    const u16* sA = &ls[s][0];
    const u16* sB = &ls[s][8192];
    const bool g1 = (i + 1 < nte);

    if (g1) ST3(o, K0G(i + 1));

    // de-fenced tile body
    {
      short8 af0[4], af1[4], bf0[4], bf1[4];
#pragma unroll
      for (int mi = 0; mi < 4; ++mi) {
        int row = wm * 64 + mi * 16 + l15;
        af0[mi] = *(const short8*)&sA[(row * 8 + (lhi ^ (row & 7))) * 8];
      }
#pragma unroll
      for (int ni = 0; ni < 4; ++ni) {
        int row = wn * 64 + ni * 16 + l15;
        bf0[ni] = *(const short8*)&sB[(row * 8 + (lhi ^ (row & 7))) * 8];
      }
#pragma unroll
      for (int mi = 0; mi < 4; ++mi)
#pragma unroll
        for (int ni = 0; ni < 4; ++ni)
          acc[mi][ni] = __builtin_amdgcn_mfma_f32_16x16x32_bf16(af0[mi], bf0[ni], acc[mi][ni], 0, 0, 0);
#pragma unroll
      for (int mi = 0; mi < 4; ++mi) {
        int row = wm * 64 + mi * 16 + l15;
        af1[mi] = *(const short8*)&sA[(row * 8 + ((4 + lhi) ^ (row & 7))) * 8];
      }
#pragma unroll
      for (int ni = 0; ni < 4; ++ni) {
        int row = wn * 64 + ni * 16 + l15;
        bf1[ni] = *(const short8*)&sB[(row * 8 + ((4 + lhi) ^ (row & 7))) * 8];
      }
#pragma unroll
      for (int mi = 0; mi < 4; ++mi)
#pragma unroll
        for (int ni = 0; ni < 4; ++ni)
          acc[mi][ni] = __builtin_amdgcn_mfma_f32_16x16x32_bf16(af1[mi], bf1[ni], acc[mi][ni], 0, 0, 0);
    }

    asm volatile("s_waitcnt vmcnt(0)" ::: "memory");
    __builtin_amdgcn_s_barrier();
  }
#undef K0G
#undef ST3

  // ---------- logprob epilogue ----------
#pragma unroll
  for (int mi = 0; mi < 4; ++mi) {
#pragma unroll
    for (int e = 0; e < 4; ++e) {
      int row = brow + wm * 64 + mi * 16 + lhi * 4 + e;
      float partial = 0.0f;
#pragma unroll
      for (int ni = 0; ni < 4; ++ni) {
        int col = bcol + wn * 64 + ni * 16 + l15;
        float l = acc[mi][ni][e] + bias[col];
        float v = bf2f(vbf[(size_t)row * N + col]);
        float sp = fmaxf(l, 0.0f) + __logf(1.0f + __expf(-fabsf(l)));
        partial += v * l - sp;
      }
#pragma unroll
      for (int off = 1; off < 16; off <<= 1)
        partial += __shfl_xor(partial, off, 64);
      if (l15 == 0) atomicAdd(&outp[row], partial);
    }
  }
}

// ---------------- launcher ----------------
extern "C" void kernel_launch(void* const* d_in, const int* in_sizes, int n_in,
                              void* d_out, int out_size, void* d_ws, size_t ws_size,
                              hipStream_t stream) {
  const float* value = (const float*)d_in[0];
  const float* W1 = (const float*)d_in[1];
  const float* b1 = (const float*)d_in[2];
  const float* W2 = (const float*)d_in[3];
  const float* b2 = (const float*)d_in[4];
  const float* W3 = (const float*)d_in[5];
  const float* b3 = (const float*)d_in[6];
  float* out = (float*)d_out;

  char* ws = (char*)d_ws;
  u16* vbf = (u16*)(ws);                        // B*D bf16
  u16* w1m = (u16*)(ws + 33554432ULL);          // H*D bf16
  u16* w2m = (u16*)(ws + 50331648ULL);          // H*H bf16
  u16* w3m = (u16*)(ws + 83886080ULL);          // D*H bf16
  u16* h1  = (u16*)(ws + 100663296ULL);         // B*H bf16
  u16* h2  = (u16*)(ws + 167772160ULL);         // B*H bf16

  hipMemsetAsync(d_out, 0, (size_t)out_size * sizeof(float), stream);

  cvt_value_kernel<<<2048, 256, 0, stream>>>(value, vbf, (BB * DD) / 4);
  mask_cvt_tile<0><<<dim3(DD / 64, HH / 64), 256, 0, stream>>>(W1, w1m, DD);
  mask_cvt_tile<1><<<dim3(HH / 64, HH / 64), 256, 0, stream>>>(W2, w2m, HH);
  mask_cvt_tile<2><<<dim3(HH / 64, DD / 64), 256, 0, stream>>>(W3, w3m, HH);

  gemm256_kernel<1><<<256, 512, 0, stream>>>(vbf, w1m, b1, h1, BB, HH, DD);
  gemm256_kernel<2><<<256, 512, 0, stream>>>(h1, w2m, b2, h2, BB, HH, HH);
  gemm3p_kernel<<<512, 512, 0, stream>>>(h2, w3m, b3, vbf, out, BB, DD, HH);
}